// Round 2
// baseline (121.533 us; speedup 1.0000x reference)
//
#include <hip/hip_runtime.h>

// ByteBitwiseFFN: out = x with +2.0 scattered into OUTPUT_LO+(res&15) and
// OUTPUT_HI+(res>>4) per row, res = bitwise-op(a,b) decoded from argmax fields.
// One wave (64 lanes) per row of 128 floats; lane l holds float2 at offset 4+2l
// (lanes 62/63 hold offsets 0..3 = mark/op flags). Each argmax window [base,base+16)
// is then an 8-aligned 8-lane group -> shfl_xor butterfly argmax, no LDS.
// Tables are redundant: and_table[a][b] == float(a&b), etc.

#define NROWS (16 * 8192)
#define DFEAT 128

__global__ __launch_bounds__(256) void bbffn_kernel(const float* __restrict__ x,
                                                    float* __restrict__ out) {
    const int lane = threadIdx.x & 63;
    const int wave = blockIdx.x * 4 + (threadIdx.x >> 6);
    const int nwaves = gridDim.x * 4;

    // per-lane feature offsets within the row
    const int o0 = (lane < 62) ? (4 + 2 * lane) : ((lane == 62) ? 0 : 2);
    const int o1 = o0 + 1;
    // window-local index of this lane's first element (valid for lanes 0..31)
    const int il = 2 * (lane & 7);

    for (int row = wave; row < NROWS; row += nwaves) {
        const float* xr = x + (size_t)row * DFEAT;
        float2 v = *reinterpret_cast<const float2*>(xr + o0);

        // local argmax over the lane's two elements (first-index tie-break)
        float m = v.x;
        int idx = il;
        if (v.y > v.x) { m = v.y; idx = il + 1; }

        // butterfly argmax within 8-lane groups (each group = one 16-elem window)
        #pragma unroll
        for (int d = 1; d <= 4; d <<= 1) {
            float mo = __shfl_xor(m, d);
            int io = __shfl_xor(idx, d);
            if (mo > m || (mo == m && io < idx)) { m = mo; idx = io; }
        }

        // window argmaxes live in lanes 0,8,16,24 (groups for offsets 4,20,36,52)
        const int a_lo = __shfl(idx, 0);
        const int a_hi = __shfl(idx, 8);
        const int b_lo = __shfl(idx, 16);
        const int b_hi = __shfl(idx, 24);
        const int a = a_lo | (a_hi << 4);
        const int b = b_lo | (b_hi << 4);

        // flags: x[0],x[1] in lane 62; x[2],x[3] in lane 63
        const float f_mark = __shfl(v.x, 62);
        const float f_and  = __shfl(v.y, 62);
        const float f_or   = __shfl(v.x, 63);
        const float f_xor  = __shfl(v.y, 63);

        const bool is_and = f_and > 0.5f;
        const bool is_or  = f_or  > 0.5f;
        const bool is_xor = f_xor > 0.5f;

        // LUT values are exactly the bitwise ops; if/elif priority AND,OR,XOR(default)
        const int res = is_and ? (a & b) : (is_or ? (a | b) : (a ^ b));
        const bool active = (f_mark >= 0.5f) && (is_and || is_or || is_xor);
        const float w = active ? 2.0f : 0.0f;

        const int p_lo = 68 + (res & 15);
        const int p_hi = 84 + (res >> 4);

        float2 o = v;
        if (o0 == p_lo || o0 == p_hi) o.x += w;
        if (o1 == p_lo || o1 == p_hi) o.y += w;

        *reinterpret_cast<float2*>(out + (size_t)row * DFEAT + o0) = o;
    }
}

extern "C" void kernel_launch(void* const* d_in, const int* in_sizes, int n_in,
                              void* d_out, int out_size, void* d_ws, size_t ws_size,
                              hipStream_t stream) {
    const float* x = (const float*)d_in[0];
    float* out = (float*)d_out;
    // 2048 blocks x 4 waves = 8192 waves; 131072 rows -> exactly 16 rows/wave
    dim3 grid(2048), block(256);
    hipLaunchKernelGGL(bbffn_kernel, grid, block, 0, stream, x, out);
}

// Round 3
// 121.219 us; speedup vs baseline: 1.0026x; 1.0026x over previous
//
#include <hip/hip_runtime.h>

// ByteBitwiseFFN: out = x with +2.0 scattered into OUTPUT_LO+(res&15) and
// OUTPUT_HI+(res>>4) per row, res = bitwise-op(a,b) decoded from argmax fields.
// One wave (64 lanes) per row; lane l holds float2 at offset 4+2l (lanes 62/63
// hold offsets 0..3 = mark/op flags). Each argmax window is an 8-aligned 8-lane
// group -> 3-step shfl_xor butterfly argmax. Tables == bitwise ops, no gather.
// R3: 4 independent rows per wave iteration, phase-interleaved, to fix the
// latency-bound serial chain (R2: 121us at only 1.1 TB/s effective).

#define NROWS (16 * 8192)
#define DFEAT 128
#define UNROLL 4

__global__ __launch_bounds__(256, 4) void bbffn_kernel(const float* __restrict__ x,
                                                       float* __restrict__ out) {
    const int lane = threadIdx.x & 63;
    const int wave = blockIdx.x * 4 + (threadIdx.x >> 6);
    const int nwaves = gridDim.x * 4;   // 8192

    // per-lane feature offsets within the row
    const int o0 = (lane < 62) ? (4 + 2 * lane) : ((lane == 62) ? 0 : 2);
    const int o1 = o0 + 1;
    // window-local index of this lane's first element (valid for lanes 0..31)
    const int il = 2 * (lane & 7);

    // 131072 rows / 8192 waves = 16 rows/wave = 4 iterations x UNROLL
    for (int it = 0; it < NROWS / (8192 * UNROLL); ++it) {
        int row[UNROLL];
        float2 v[UNROLL];
        float m[UNROLL];
        int idx[UNROLL];

        // phase 1: issue all loads (independent)
        #pragma unroll
        for (int k = 0; k < UNROLL; ++k) {
            row[k] = wave + (it * UNROLL + k) * nwaves;
            v[k] = *reinterpret_cast<const float2*>(x + (size_t)row[k] * DFEAT + o0);
        }

        // phase 2: local argmax (first-index tie-break)
        #pragma unroll
        for (int k = 0; k < UNROLL; ++k) {
            m[k] = v[k].x;
            idx[k] = il;
            if (v[k].y > v[k].x) { m[k] = v[k].y; idx[k] = il + 1; }
        }

        // phase 3: butterfly argmax within 8-lane groups, 4 rows interleaved
        #pragma unroll
        for (int d = 1; d <= 4; d <<= 1) {
            #pragma unroll
            for (int k = 0; k < UNROLL; ++k) {
                float mo = __shfl_xor(m[k], d);
                int io = __shfl_xor(idx[k], d);
                if (mo > m[k] || (mo == m[k] && io < idx[k])) { m[k] = mo; idx[k] = io; }
            }
        }

        // phase 4: broadcasts + decode + predicated add + store
        #pragma unroll
        for (int k = 0; k < UNROLL; ++k) {
            const int a = __shfl(idx[k], 0) | (__shfl(idx[k], 8) << 4);
            const int b = __shfl(idx[k], 16) | (__shfl(idx[k], 24) << 4);

            const float f_mark = __shfl(v[k].x, 62);
            const float f_and  = __shfl(v[k].y, 62);
            const float f_or   = __shfl(v[k].x, 63);
            const float f_xor  = __shfl(v[k].y, 63);

            const bool is_and = f_and > 0.5f;
            const bool is_or  = f_or  > 0.5f;
            const bool is_xor = f_xor > 0.5f;

            const int res = is_and ? (a & b) : (is_or ? (a | b) : (a ^ b));
            const bool active = (f_mark >= 0.5f) && (is_and || is_or || is_xor);
            const float w = active ? 2.0f : 0.0f;

            const int p_lo = 68 + (res & 15);
            const int p_hi = 84 + (res >> 4);

            float2 o = v[k];
            if (o0 == p_lo || o0 == p_hi) o.x += w;
            if (o1 == p_lo || o1 == p_hi) o.y += w;

            *reinterpret_cast<float2*>(out + (size_t)row[k] * DFEAT + o0) = o;
        }
    }
}

extern "C" void kernel_launch(void* const* d_in, const int* in_sizes, int n_in,
                              void* d_out, int out_size, void* d_ws, size_t ws_size,
                              hipStream_t stream) {
    const float* x = (const float*)d_in[0];
    float* out = (float*)d_out;
    // 2048 blocks x 4 waves = 8192 waves; 131072 rows -> 4 iters x 4 rows/wave
    dim3 grid(2048), block(256);
    hipLaunchKernelGGL(bbffn_kernel, grid, block, 0, stream, x, out);
}